// Round 7
// baseline (140.663 us; speedup 1.0000x reference)
//
#include <hip/hip_runtime.h>

#define NN 50000
#define NE 800000
#define DD 128
#define BSH 6
#define BSZ 64                                // nodes per bucket
#define NBUCK ((NN + BSZ - 1) / BSZ)          // 782
#define NBLK 256                              // edge-partition blocks
#define EPB ((NE + NBLK - 1) / NBLK)          // 3125
#define CAP 2048                              // edges per LDS chunk in gather

__device__ __forceinline__ unsigned short f2bf(float x) {
    unsigned u = __float_as_uint(x);
    unsigned r = u + 0x7FFF + ((u >> 16) & 1);   // round-to-nearest-even
    return (unsigned short)(r >> 16);
}
__device__ __forceinline__ float bf2f(unsigned short x) {
    return __uint_as_float((unsigned)x << 16);
}

// K1: per-block LDS histograms of dst>>6 and src>>6 (no global atomics)
__global__ void hist_kernel(const int* __restrict__ src, const int* __restrict__ dst,
                            int* __restrict__ histD, int* __restrict__ histS) {
    __shared__ int hD[NBUCK], hS[NBUCK];
    int t = threadIdx.x, blk = blockIdx.x;
    for (int b = t; b < NBUCK; b += 256) { hD[b] = 0; hS[b] = 0; }
    __syncthreads();
    int beg = blk * EPB, end = min(beg + EPB, NE);
    for (int i = beg + t; i < end; i += 256) {
        atomicAdd(&hD[dst[i] >> BSH], 1);
        atomicAdd(&hS[src[i] >> BSH], 1);
    }
    __syncthreads();
    for (int b = t; b < NBUCK; b += 256) {
        histD[b * NBLK + blk] = hD[b];
        histS[b * NBLK + blk] = hS[b];
    }
}

// K2a: per-bin totals (both tables; blockIdx selects table+bin)
__global__ void binsum_kernel(const int* __restrict__ histD, const int* __restrict__ histS,
                              int* __restrict__ SD, int* __restrict__ SS) {
    __shared__ int tmp[256];
    int t = threadIdx.x, b = blockIdx.x;
    const int* hist = (b < NBUCK) ? histD : histS;
    int* S = (b < NBUCK) ? SD : SS;
    int bin = (b < NBUCK) ? b : b - NBUCK;
    tmp[t] = hist[bin * NBLK + t];
    __syncthreads();
    for (int off = 128; off > 0; off >>= 1) {
        if (t < off) tmp[t] += tmp[t + off];
        __syncthreads();
    }
    if (t == 0) S[bin] = tmp[0];
}

// K2b: offsets[bin][blk] = binBase(bin) + prefix_within_bin(blk); in-place on hist.
__global__ void offsets_kernel(int* __restrict__ histD, int* __restrict__ histS,
                               const int* __restrict__ SD, const int* __restrict__ SS,
                               int* __restrict__ baseD, int* __restrict__ baseS) {
    __shared__ int s[1024];
    __shared__ int col[NBLK];
    int t = threadIdx.x, b = blockIdx.x;
    int* hist = (b < NBUCK) ? histD : histS;
    const int* S = (b < NBUCK) ? SD : SS;
    int* base = (b < NBUCK) ? baseD : baseS;
    int bin = (b < NBUCK) ? b : b - NBUCK;
    s[t] = (t < NBUCK) ? S[t] : 0;
    __syncthreads();
    for (int off = 1; off < 1024; off <<= 1) {
        int x = (t >= off) ? s[t - off] : 0;
        __syncthreads();
        s[t] += x;
        __syncthreads();
    }
    int binBase = s[bin] - S[bin];   // exclusive across bins
    if (t < NBLK) col[t] = hist[bin * NBLK + t];
    __syncthreads();
    int cv = (t < NBLK) ? col[t] : 0;
    for (int off = 1; off < NBLK; off <<= 1) {
        int x = (t < NBLK && t >= off) ? col[t - off] : 0;
        __syncthreads();
        if (t < NBLK) col[t] += x;
        __syncthreads();
    }
    if (t < NBLK) hist[bin * NBLK + t] = binBase + col[t] - cv;   // exclusive within bin
    if (t == 0) base[bin] = binBase;
}

// K3: scatter edges into dst-buckets (packed src|lo<<16) and src_lo bytes into src-buckets.
__global__ void scatter_kernel(const int* __restrict__ src, const int* __restrict__ dst,
                               const int* __restrict__ offsD, const int* __restrict__ offsS,
                               unsigned int* __restrict__ sortedD,
                               unsigned char* __restrict__ sortedS) {
    __shared__ int curD[NBUCK], curS[NBUCK];
    int t = threadIdx.x, blk = blockIdx.x;
    for (int b = t; b < NBUCK; b += 256) {
        curD[b] = offsD[b * NBLK + blk];
        curS[b] = offsS[b * NBLK + blk];
    }
    __syncthreads();
    int beg = blk * EPB, end = min(beg + EPB, NE);
    for (int i = beg + t; i < end; i += 256) {
        int sv = src[i], dv = dst[i];
        int pD = atomicAdd(&curD[dv >> BSH], 1);
        sortedD[pD] = (unsigned)sv | ((unsigned)(dv & (BSZ - 1)) << 16);
        int pS = atomicAdd(&curS[sv >> BSH], 1);
        sortedS[pS] = (unsigned char)(sv & (BSZ - 1));
    }
}

// K4s: per src-bucket: LDS out-degree histogram -> build bf16 h rows (fused norm_l).
__global__ void hbuild_kernel(const unsigned char* __restrict__ sortedS,
                              const int* __restrict__ baseS, const int* __restrict__ feat,
                              const float* __restrict__ emb, ushort2* __restrict__ h) {
    __shared__ int hc[BSZ];
    int t = threadIdx.x, bin = blockIdx.x;
    if (t < BSZ) hc[t] = 0;
    __syncthreads();
    int beg = baseS[bin];
    int end = (bin == NBUCK - 1) ? NE : baseS[bin + 1];
    for (int i = beg + t; i < end; i += 256) atomicAdd(&hc[sortedS[i]], 1);
    __syncthreads();
    int w = t >> 6, lane = t & 63;
    for (int k = 0; k < 16; k++) {
        int lo = (w << 4) + k;           // wave w owns 16 consecutive nodes
        int n = (bin << BSH) + lo;
        if (n >= NN) break;
        float nl = rsqrtf((float)max(hc[lo], 1));
        int f = feat[n];
        float2 v = ((const float2*)(emb + (size_t)f * DD))[lane];
        h[(size_t)n * 64 + lane] = make_ushort2(f2bf(v.x * nl), f2bf(v.y * nl));
    }
}

// K5: per dst-bucket: LDS counting-sort by dst_lo, then 8 waves gather h rows with
// x4-unrolled independent loads, fused norm_r + bias, single coalesced write.
__global__ void __launch_bounds__(512) gather_kernel(
        const unsigned int* __restrict__ sortedD, const int* __restrict__ baseD,
        const ushort2* __restrict__ h, const float* __restrict__ bias,
        float* __restrict__ out) {
    __shared__ unsigned short eds[CAP];
    __shared__ int lh[BSZ], lbase[BSZ], lcur[BSZ];
    int t = threadIdx.x, bin = blockIdx.x;
    int w = t >> 6, lane = t & 63;
    int beg = baseD[bin];
    int end = (bin == NBUCK - 1) ? NE : baseD[bin + 1];
    float2 acc[8];
    int tcnt[8];
    for (int k = 0; k < 8; k++) { acc[k] = make_float2(0.f, 0.f); tcnt[k] = 0; }
    for (int cb = beg; cb < end; cb += CAP) {
        int m = min(end - cb, CAP);
        if (t < BSZ) lh[t] = 0;
        __syncthreads();
        unsigned int er[4];
        int nt = 0;
        for (int i = t; i < m; i += 512) {
            unsigned int e = sortedD[cb + i];
            er[nt++] = e;
            atomicAdd(&lh[e >> 16], 1);
        }
        __syncthreads();
        int cv = (t < BSZ) ? lh[t] : 0;
        if (t < BSZ) lbase[t] = cv;
        __syncthreads();
        for (int off = 1; off < BSZ; off <<= 1) {
            int x = (t < BSZ && t >= off) ? lbase[t - off] : 0;
            __syncthreads();
            if (t < BSZ) lbase[t] += x;
            __syncthreads();
        }
        if (t < BSZ) { lbase[t] -= cv; lcur[t] = lbase[t]; }
        __syncthreads();
        for (int j = 0; j < nt; j++) {
            int pos = atomicAdd(&lcur[er[j] >> 16], 1);
            eds[pos] = (unsigned short)(er[j] & 0xFFFF);
        }
        __syncthreads();
        for (int k = 0; k < 8; k++) {
            int lo = (w << 3) + k;       // wave w owns 8 consecutive nodes
            int c = lh[lo], b0 = lbase[lo];
            tcnt[k] += c;
            int j = 0;
            for (; j + 3 < c; j += 4) {
                int s0 = eds[b0 + j];
                int s1 = eds[b0 + j + 1];
                int s2 = eds[b0 + j + 2];
                int s3 = eds[b0 + j + 3];
                ushort2 v0 = h[(size_t)s0 * 64 + lane];
                ushort2 v1 = h[(size_t)s1 * 64 + lane];
                ushort2 v2 = h[(size_t)s2 * 64 + lane];
                ushort2 v3 = h[(size_t)s3 * 64 + lane];
                acc[k].x += bf2f(v0.x) + bf2f(v1.x) + bf2f(v2.x) + bf2f(v3.x);
                acc[k].y += bf2f(v0.y) + bf2f(v1.y) + bf2f(v2.y) + bf2f(v3.y);
            }
            for (; j < c; j++) {
                int s0 = eds[b0 + j];
                ushort2 v0 = h[(size_t)s0 * 64 + lane];
                acc[k].x += bf2f(v0.x);
                acc[k].y += bf2f(v0.y);
            }
        }
        __syncthreads();
    }
    float2 bi = ((const float2*)bias)[lane];
    for (int k = 0; k < 8; k++) {
        int lo = (w << 3) + k;
        int n = (bin << BSH) + lo;
        if (n < NN) {
            float nr = rsqrtf((float)max(tcnt[k], 1));
            ((float2*)(out + (size_t)n * DD))[lane] =
                make_float2(acc[k].x * nr + bi.x, acc[k].y * nr + bi.y);
        }
    }
}

extern "C" void kernel_launch(void* const* d_in, const int* in_sizes, int n_in,
                              void* d_out, int out_size, void* d_ws, size_t ws_size,
                              hipStream_t stream) {
    const int* feat = (const int*)d_in[0];
    const int* src  = (const int*)d_in[1];
    const int* dst  = (const int*)d_in[2];
    const float* emb  = (const float*)d_in[3];
    const float* bias = (const float*)d_in[4];
    float* out = (float*)d_out;

    // Workspace layout (~18.5 MB; byte array last to keep 4B alignment)
    int* histD = (int*)d_ws;                         // NBUCK*NBLK
    int* histS = histD + NBUCK * NBLK;               // NBUCK*NBLK
    int* SD    = histS + NBUCK * NBLK;               // NBUCK (padded 800)
    int* SS    = SD + 800;                           // NBUCK
    int* baseD = SS + 800;                           // NBUCK
    int* baseS = baseD + 800;                        // NBUCK
    unsigned int* sortedD = (unsigned int*)(baseS + 800);    // NE
    ushort2* h = (ushort2*)(sortedD + NE);           // NN*64 ushort2 (12.8 MB)
    unsigned char* sortedS = (unsigned char*)(h + (size_t)NN * 64); // NE bytes

    hist_kernel<<<NBLK, 256, 0, stream>>>(src, dst, histD, histS);
    binsum_kernel<<<2 * NBUCK, 256, 0, stream>>>(histD, histS, SD, SS);
    offsets_kernel<<<2 * NBUCK, 1024, 0, stream>>>(histD, histS, SD, SS, baseD, baseS);
    scatter_kernel<<<NBLK, 256, 0, stream>>>(src, dst, histD, histS, sortedD, sortedS);
    hbuild_kernel<<<NBUCK, 256, 0, stream>>>(sortedS, baseS, feat, emb, h);
    gather_kernel<<<NBUCK, 512, 0, stream>>>(sortedD, baseD, h, bias, out);
}

// Round 8
// 102.252 us; speedup vs baseline: 1.3757x; 1.3757x over previous
//
#include <hip/hip_runtime.h>

#define NN 50000
#define NE 800000
#define DD 128
#define BSH 6
#define BSZ 64                                // nodes per bucket
#define NBUCK ((NN + BSZ - 1) / BSZ)          // 782
#define NBLK 256                              // edge-partition blocks
#define EPB ((NE + NBLK - 1) / NBLK)          // 3125

__device__ __forceinline__ unsigned short f2bf(float x) {
    unsigned u = __float_as_uint(x);
    unsigned r = u + 0x7FFF + ((u >> 16) & 1);   // round-to-nearest-even
    return (unsigned short)(r >> 16);
}
__device__ __forceinline__ float bf2f(unsigned short x) {
    return __uint_as_float((unsigned)x << 16);
}

// K1: per-block LDS histograms of dst>>6 and src>>6 (no global atomics)
__global__ void hist_kernel(const int* __restrict__ src, const int* __restrict__ dst,
                            int* __restrict__ histD, int* __restrict__ histS) {
    __shared__ int hD[NBUCK], hS[NBUCK];
    int t = threadIdx.x, blk = blockIdx.x;
    for (int b = t; b < NBUCK; b += 256) { hD[b] = 0; hS[b] = 0; }
    __syncthreads();
    int beg = blk * EPB, end = min(beg + EPB, NE);
    for (int i = beg + t; i < end; i += 256) {
        atomicAdd(&hD[dst[i] >> BSH], 1);
        atomicAdd(&hS[src[i] >> BSH], 1);
    }
    __syncthreads();
    for (int b = t; b < NBUCK; b += 256) {
        histD[b * NBLK + blk] = hD[b];
        histS[b * NBLK + blk] = hS[b];
    }
}

// K2a: per-bin totals (both tables; blockIdx selects table+bin)
__global__ void binsum_kernel(const int* __restrict__ histD, const int* __restrict__ histS,
                              int* __restrict__ SD, int* __restrict__ SS) {
    __shared__ int tmp[256];
    int t = threadIdx.x, b = blockIdx.x;
    const int* hist = (b < NBUCK) ? histD : histS;
    int* S = (b < NBUCK) ? SD : SS;
    int bin = (b < NBUCK) ? b : b - NBUCK;
    tmp[t] = hist[bin * NBLK + t];
    __syncthreads();
    for (int off = 128; off > 0; off >>= 1) {
        if (t < off) tmp[t] += tmp[t + off];
        __syncthreads();
    }
    if (t == 0) S[bin] = tmp[0];
}

// K2b: offsets[bin][blk] = binBase(bin) + prefix_within_bin(blk); in-place on hist.
__global__ void offsets_kernel(int* __restrict__ histD, int* __restrict__ histS,
                               const int* __restrict__ SD, const int* __restrict__ SS,
                               int* __restrict__ baseD, int* __restrict__ baseS) {
    __shared__ int s[1024];
    __shared__ int col[NBLK];
    int t = threadIdx.x, b = blockIdx.x;
    int* hist = (b < NBUCK) ? histD : histS;
    const int* S = (b < NBUCK) ? SD : SS;
    int* base = (b < NBUCK) ? baseD : baseS;
    int bin = (b < NBUCK) ? b : b - NBUCK;
    s[t] = (t < NBUCK) ? S[t] : 0;
    __syncthreads();
    for (int off = 1; off < 1024; off <<= 1) {
        int x = (t >= off) ? s[t - off] : 0;
        __syncthreads();
        s[t] += x;
        __syncthreads();
    }
    int binBase = s[bin] - S[bin];   // exclusive across bins
    if (t < NBLK) col[t] = hist[bin * NBLK + t];
    __syncthreads();
    int cv = (t < NBLK) ? col[t] : 0;
    for (int off = 1; off < NBLK; off <<= 1) {
        int x = (t < NBLK && t >= off) ? col[t - off] : 0;
        __syncthreads();
        if (t < NBLK) col[t] += x;
        __syncthreads();
    }
    if (t < NBLK) hist[bin * NBLK + t] = binBase + col[t] - cv;   // exclusive within bin
    if (t == 0) base[bin] = binBase;
}

// K3: scatter edges into dst-buckets (packed src|lo<<16) and src_lo bytes into src-buckets.
__global__ void scatter_kernel(const int* __restrict__ src, const int* __restrict__ dst,
                               const int* __restrict__ offsD, const int* __restrict__ offsS,
                               unsigned int* __restrict__ sortedD,
                               unsigned char* __restrict__ sortedS) {
    __shared__ int curD[NBUCK], curS[NBUCK];
    int t = threadIdx.x, blk = blockIdx.x;
    for (int b = t; b < NBUCK; b += 256) {
        curD[b] = offsD[b * NBLK + blk];
        curS[b] = offsS[b * NBLK + blk];
    }
    __syncthreads();
    int beg = blk * EPB, end = min(beg + EPB, NE);
    for (int i = beg + t; i < end; i += 256) {
        int sv = src[i], dv = dst[i];
        int pD = atomicAdd(&curD[dv >> BSH], 1);
        sortedD[pD] = (unsigned)sv | ((unsigned)(dv & (BSZ - 1)) << 16);
        int pS = atomicAdd(&curS[sv >> BSH], 1);
        sortedS[pS] = (unsigned char)(sv & (BSZ - 1));
    }
}

// K4: per src-bucket: LDS out-degree histogram -> build bf16 h rows (fused norm_l).
__global__ void hbuild_kernel(const unsigned char* __restrict__ sortedS,
                              const int* __restrict__ baseS, const int* __restrict__ feat,
                              const float* __restrict__ emb, ushort2* __restrict__ h) {
    __shared__ int hc[BSZ];
    int t = threadIdx.x, bin = blockIdx.x;
    if (t < BSZ) hc[t] = 0;
    __syncthreads();
    int beg = baseS[bin];
    int end = (bin == NBUCK - 1) ? NE : baseS[bin + 1];
    for (int i = beg + t; i < end; i += 256) atomicAdd(&hc[sortedS[i]], 1);
    __syncthreads();
    int w = t >> 6, lane = t & 63;
    for (int k = 0; k < 16; k++) {
        int lo = (w << 4) + k;
        int n = (bin << BSH) + lo;
        if (n >= NN) break;
        float nl = rsqrtf((float)max(hc[lo], 1));
        int f = feat[n];
        float2 v = ((const float2*)(emb + (size_t)f * DD))[lane];
        h[(size_t)n * 64 + lane] = make_ushort2(f2bf(v.x * nl), f2bf(v.y * nl));
    }
}

// K5: per dst-bucket: LDS counting-sort by dst_lo -> per-node contiguous ushort src
// lists in global (srcfine) + per-node base/cnt. All atomics are LDS.
__global__ void finesort_kernel(const unsigned int* __restrict__ sortedD,
                                const int* __restrict__ baseD,
                                int* __restrict__ baseN, int* __restrict__ cntN,
                                unsigned short* __restrict__ srcfine) {
    __shared__ int lh[BSZ], lbase[BSZ], lcur[BSZ];
    int t = threadIdx.x, bin = blockIdx.x;
    int beg = baseD[bin];
    int end = (bin == NBUCK - 1) ? NE : baseD[bin + 1];
    if (t < BSZ) lh[t] = 0;
    __syncthreads();
    for (int i = beg + t; i < end; i += 256) atomicAdd(&lh[sortedD[i] >> 16], 1);
    __syncthreads();
    if (t < BSZ) {                         // first wave: shfl exclusive scan of 64
        int v = lh[t];
        int x = v;
        for (int off = 1; off < 64; off <<= 1) {
            int y = __shfl_up(x, off);
            if (t >= off) x += y;
        }
        int excl = beg + x - v;
        lbase[t] = excl;
        lcur[t] = excl;
        int n = (bin << BSH) + t;
        if (n < NN) { baseN[n] = excl; cntN[n] = v; }
    }
    __syncthreads();
    for (int i = beg + t; i < end; i += 256) {
        unsigned e = sortedD[i];
        int pos = atomicAdd(&lcur[e >> 16], 1);
        srcfine[pos] = (unsigned short)(e & 0xFFFF);
    }
}

// K6: one wave per dst node. Batch index load + shfl broadcast; x4-unrolled
// independent 256B h-row loads; fp32 accumulate; fused norm_r + bias.
__global__ void gatherA_kernel(const unsigned short* __restrict__ srcfine,
                               const int* __restrict__ baseN, const int* __restrict__ cntN,
                               const ushort2* __restrict__ h, const float* __restrict__ bias,
                               float* __restrict__ out) {
    int wid = (blockIdx.x * blockDim.x + threadIdx.x) >> 6;
    int lane = threadIdx.x & 63;
    if (wid >= NN) return;
    int cnt = cntN[wid];
    int beg = baseN[wid];
    float ax = 0.f, ay = 0.f;
    for (int b0 = 0; b0 < cnt; b0 += 64) {
        int m = min(cnt - b0, 64);
        int idx = (lane < m) ? (int)srcfine[beg + b0 + lane] : 0;
        int j = 0;
        for (; j + 3 < m; j += 4) {
            int s0 = __shfl(idx, j);
            int s1 = __shfl(idx, j + 1);
            int s2 = __shfl(idx, j + 2);
            int s3 = __shfl(idx, j + 3);
            ushort2 v0 = h[(size_t)s0 * 64 + lane];
            ushort2 v1 = h[(size_t)s1 * 64 + lane];
            ushort2 v2 = h[(size_t)s2 * 64 + lane];
            ushort2 v3 = h[(size_t)s3 * 64 + lane];
            ax += bf2f(v0.x) + bf2f(v1.x) + bf2f(v2.x) + bf2f(v3.x);
            ay += bf2f(v0.y) + bf2f(v1.y) + bf2f(v2.y) + bf2f(v3.y);
        }
        for (; j < m; j++) {
            int s0 = __shfl(idx, j);
            ushort2 v0 = h[(size_t)s0 * 64 + lane];
            ax += bf2f(v0.x);
            ay += bf2f(v0.y);
        }
    }
    float nr = rsqrtf((float)max(cnt, 1));
    float2 b = ((const float2*)bias)[lane];
    ((float2*)(out + (size_t)wid * DD))[lane] = make_float2(ax * nr + b.x, ay * nr + b.y);
}

extern "C" void kernel_launch(void* const* d_in, const int* in_sizes, int n_in,
                              void* d_out, int out_size, void* d_ws, size_t ws_size,
                              hipStream_t stream) {
    const int* feat = (const int*)d_in[0];
    const int* src  = (const int*)d_in[1];
    const int* dst  = (const int*)d_in[2];
    const float* emb  = (const float*)d_in[3];
    const float* bias = (const float*)d_in[4];
    float* out = (float*)d_out;

    // Workspace layout (~20.5 MB; descending alignment)
    int* histD = (int*)d_ws;                          // NBUCK*NBLK
    int* histS = histD + NBUCK * NBLK;                // NBUCK*NBLK
    int* SD    = histS + NBUCK * NBLK;                // NBUCK (padded 800)
    int* SS    = SD + 800;
    int* baseD = SS + 800;
    int* baseS = baseD + 800;
    int* baseN = baseS + 800;                         // NN
    int* cntN  = baseN + NN;                          // NN
    unsigned int* sortedD = (unsigned int*)(cntN + NN);         // NE
    ushort2* h = (ushort2*)(sortedD + NE);            // NN*64 ushort2 (12.8 MB)
    unsigned short* srcfine = (unsigned short*)(h + (size_t)NN * 64); // NE ushort
    unsigned char* sortedS = (unsigned char*)(srcfine + NE);    // NE bytes

    hist_kernel<<<NBLK, 256, 0, stream>>>(src, dst, histD, histS);
    binsum_kernel<<<2 * NBUCK, 256, 0, stream>>>(histD, histS, SD, SS);
    offsets_kernel<<<2 * NBUCK, 1024, 0, stream>>>(histD, histS, SD, SS, baseD, baseS);
    scatter_kernel<<<NBLK, 256, 0, stream>>>(src, dst, histD, histS, sortedD, sortedS);
    hbuild_kernel<<<NBUCK, 256, 0, stream>>>(sortedS, baseS, feat, emb, h);
    finesort_kernel<<<NBUCK, 256, 0, stream>>>(sortedD, baseD, baseN, cntN, srcfine);
    gatherA_kernel<<<(NN * 64 + 255) / 256, 256, 0, stream>>>(srcfine, baseN, cntN, h, bias, out);
}

// Round 9
// 86.459 us; speedup vs baseline: 1.6269x; 1.1827x over previous
//
#include <hip/hip_runtime.h>

#define NN 50000
#define NE 800000
#define DD 128
#define BSH 6
#define BSZ 64                                // nodes per bucket
#define NBUCK ((NN + BSZ - 1) / BSZ)          // 782
#define NBLK 256                              // edge-partition blocks
#define EPB ((NE + NBLK - 1) / NBLK)          // 3125

__device__ __forceinline__ unsigned short f2bf(float x) {
    unsigned u = __float_as_uint(x);
    unsigned r = u + 0x7FFF + ((u >> 16) & 1);   // round-to-nearest-even
    return (unsigned short)(r >> 16);
}
__device__ __forceinline__ float bf2f(unsigned short x) {
    return __uint_as_float((unsigned)x << 16);
}

// K1: per-block LDS histograms of dst>>6 and src>>6 (no global atomics)
__global__ void hist_kernel(const int* __restrict__ src, const int* __restrict__ dst,
                            int* __restrict__ histD, int* __restrict__ histS) {
    __shared__ int hD[NBUCK], hS[NBUCK];
    int t = threadIdx.x, blk = blockIdx.x;
    for (int b = t; b < NBUCK; b += 256) { hD[b] = 0; hS[b] = 0; }
    __syncthreads();
    int beg = blk * EPB, end = min(beg + EPB, NE);
    for (int i = beg + t; i < end; i += 256) {
        atomicAdd(&hD[dst[i] >> BSH], 1);
        atomicAdd(&hS[src[i] >> BSH], 1);
    }
    __syncthreads();
    for (int b = t; b < NBUCK; b += 256) {
        histD[b * NBLK + blk] = hD[b];
        histS[b * NBLK + blk] = hS[b];
    }
}

// K2: within-bin exclusive scan over the 256 block-entries (in place) + bin total.
__global__ void within_kernel(int* __restrict__ histD, int* __restrict__ histS,
                              int* __restrict__ SD, int* __restrict__ SS) {
    __shared__ int col[NBLK];
    int t = threadIdx.x, b = blockIdx.x;
    int* hist = (b < NBUCK) ? histD : histS;
    int* S = (b < NBUCK) ? SD : SS;
    int bin = (b < NBUCK) ? b : b - NBUCK;
    int v = hist[bin * NBLK + t];
    col[t] = v;
    __syncthreads();
    for (int off = 1; off < NBLK; off <<= 1) {
        int x = (t >= off) ? col[t - off] : 0;
        __syncthreads();
        col[t] += x;
        __syncthreads();
    }
    hist[bin * NBLK + t] = col[t] - v;          // exclusive within bin
    if (t == NBLK - 1) S[bin] = col[t];         // bin total
}

// K3: single block: exclusive scan of both bin-total arrays -> bucket bases.
__global__ void scan_kernel(const int* __restrict__ SD, const int* __restrict__ SS,
                            int* __restrict__ baseD, int* __restrict__ baseS) {
    __shared__ int s[1024];
    int t = threadIdx.x;
    for (int pass = 0; pass < 2; pass++) {
        const int* S = pass ? SS : SD;
        int* base = pass ? baseS : baseD;
        int v = (t < NBUCK) ? S[t] : 0;
        s[t] = v;
        __syncthreads();
        for (int off = 1; off < 1024; off <<= 1) {
            int x = (t >= off) ? s[t - off] : 0;
            __syncthreads();
            s[t] += x;
            __syncthreads();
        }
        if (t < NBUCK) base[t] = s[t] - v;
        __syncthreads();
    }
}

// K4: scatter edges into dst-buckets (packed src|lo<<16) and src_lo bytes into
// src-buckets; LDS cursors seeded with base[bin] + within-bin offset.
__global__ void scatter_kernel(const int* __restrict__ src, const int* __restrict__ dst,
                               const int* __restrict__ offsD, const int* __restrict__ offsS,
                               const int* __restrict__ baseD, const int* __restrict__ baseS,
                               unsigned int* __restrict__ sortedD,
                               unsigned char* __restrict__ sortedS) {
    __shared__ int curD[NBUCK], curS[NBUCK];
    int t = threadIdx.x, blk = blockIdx.x;
    for (int b = t; b < NBUCK; b += 256) {
        curD[b] = baseD[b] + offsD[b * NBLK + blk];
        curS[b] = baseS[b] + offsS[b * NBLK + blk];
    }
    __syncthreads();
    int beg = blk * EPB, end = min(beg + EPB, NE);
    for (int i = beg + t; i < end; i += 256) {
        int sv = src[i], dv = dst[i];
        int pD = atomicAdd(&curD[dv >> BSH], 1);
        sortedD[pD] = (unsigned)sv | ((unsigned)(dv & (BSZ - 1)) << 16);
        int pS = atomicAdd(&curS[sv >> BSH], 1);
        sortedS[pS] = (unsigned char)(sv & (BSZ - 1));
    }
}

// K5 fused: blocks [0,NBUCK) = finesort of dst-bucket; [NBUCK,2*NBUCK) = hbuild of
// src-bucket. Both depend only on scatter.
__global__ void finehb_kernel(const unsigned int* __restrict__ sortedD,
                              const unsigned char* __restrict__ sortedS,
                              const int* __restrict__ baseD, const int* __restrict__ baseS,
                              const int* __restrict__ feat, const float* __restrict__ emb,
                              int* __restrict__ baseN, int* __restrict__ cntN,
                              unsigned short* __restrict__ srcfine,
                              ushort2* __restrict__ h) {
    __shared__ int lh[BSZ], lcur[BSZ];
    int t = threadIdx.x;
    if (blockIdx.x < NBUCK) {
        int bin = blockIdx.x;
        int beg = baseD[bin];
        int end = (bin == NBUCK - 1) ? NE : baseD[bin + 1];
        if (t < BSZ) lh[t] = 0;
        __syncthreads();
        for (int i = beg + t; i < end; i += 256) atomicAdd(&lh[sortedD[i] >> 16], 1);
        __syncthreads();
        if (t < BSZ) {                     // wave 0: shfl exclusive scan of 64
            int v = lh[t];
            int x = v;
            for (int off = 1; off < 64; off <<= 1) {
                int y = __shfl_up(x, off);
                if (t >= off) x += y;
            }
            int excl = beg + x - v;
            lcur[t] = excl;
            int n = (bin << BSH) + t;
            if (n < NN) { baseN[n] = excl; cntN[n] = v; }
        }
        __syncthreads();
        for (int i = beg + t; i < end; i += 256) {
            unsigned e = sortedD[i];
            int pos = atomicAdd(&lcur[e >> 16], 1);
            srcfine[pos] = (unsigned short)(e & 0xFFFF);
        }
    } else {
        int bin = blockIdx.x - NBUCK;
        int beg = baseS[bin];
        int end = (bin == NBUCK - 1) ? NE : baseS[bin + 1];
        if (t < BSZ) lh[t] = 0;
        __syncthreads();
        for (int i = beg + t; i < end; i += 256) atomicAdd(&lh[sortedS[i]], 1);
        __syncthreads();
        int w = t >> 6, lane = t & 63;
        for (int k = 0; k < 16; k++) {
            int lo = (w << 4) + k;
            int n = (bin << BSH) + lo;
            if (n >= NN) break;
            float nl = rsqrtf((float)max(lh[lo], 1));
            int f = feat[n];
            float2 v = ((const float2*)(emb + (size_t)f * DD))[lane];
            h[(size_t)n * 64 + lane] = make_ushort2(f2bf(v.x * nl), f2bf(v.y * nl));
        }
    }
}

// K6: one wave per dst node. Batch index load + shfl broadcast; x8-unrolled
// independent 256B h-row loads; fp32 accumulate; fused norm_r + bias.
__global__ void gatherA_kernel(const unsigned short* __restrict__ srcfine,
                               const int* __restrict__ baseN, const int* __restrict__ cntN,
                               const ushort2* __restrict__ h, const float* __restrict__ bias,
                               float* __restrict__ out) {
    int wid = (blockIdx.x * blockDim.x + threadIdx.x) >> 6;
    int lane = threadIdx.x & 63;
    if (wid >= NN) return;
    int cnt = cntN[wid];
    int beg = baseN[wid];
    float ax = 0.f, ay = 0.f;
    for (int b0 = 0; b0 < cnt; b0 += 64) {
        int m = min(cnt - b0, 64);
        int idx = (lane < m) ? (int)srcfine[beg + b0 + lane] : 0;
        int j = 0;
        for (; j + 7 < m; j += 8) {
            int s0 = __shfl(idx, j);
            int s1 = __shfl(idx, j + 1);
            int s2 = __shfl(idx, j + 2);
            int s3 = __shfl(idx, j + 3);
            int s4 = __shfl(idx, j + 4);
            int s5 = __shfl(idx, j + 5);
            int s6 = __shfl(idx, j + 6);
            int s7 = __shfl(idx, j + 7);
            ushort2 v0 = h[(size_t)s0 * 64 + lane];
            ushort2 v1 = h[(size_t)s1 * 64 + lane];
            ushort2 v2 = h[(size_t)s2 * 64 + lane];
            ushort2 v3 = h[(size_t)s3 * 64 + lane];
            ushort2 v4 = h[(size_t)s4 * 64 + lane];
            ushort2 v5 = h[(size_t)s5 * 64 + lane];
            ushort2 v6 = h[(size_t)s6 * 64 + lane];
            ushort2 v7 = h[(size_t)s7 * 64 + lane];
            ax += bf2f(v0.x) + bf2f(v1.x) + bf2f(v2.x) + bf2f(v3.x)
                + bf2f(v4.x) + bf2f(v5.x) + bf2f(v6.x) + bf2f(v7.x);
            ay += bf2f(v0.y) + bf2f(v1.y) + bf2f(v2.y) + bf2f(v3.y)
                + bf2f(v4.y) + bf2f(v5.y) + bf2f(v6.y) + bf2f(v7.y);
        }
        for (; j + 3 < m; j += 4) {
            int s0 = __shfl(idx, j);
            int s1 = __shfl(idx, j + 1);
            int s2 = __shfl(idx, j + 2);
            int s3 = __shfl(idx, j + 3);
            ushort2 v0 = h[(size_t)s0 * 64 + lane];
            ushort2 v1 = h[(size_t)s1 * 64 + lane];
            ushort2 v2 = h[(size_t)s2 * 64 + lane];
            ushort2 v3 = h[(size_t)s3 * 64 + lane];
            ax += bf2f(v0.x) + bf2f(v1.x) + bf2f(v2.x) + bf2f(v3.x);
            ay += bf2f(v0.y) + bf2f(v1.y) + bf2f(v2.y) + bf2f(v3.y);
        }
        for (; j < m; j++) {
            int s0 = __shfl(idx, j);
            ushort2 v0 = h[(size_t)s0 * 64 + lane];
            ax += bf2f(v0.x);
            ay += bf2f(v0.y);
        }
    }
    float nr = rsqrtf((float)max(cnt, 1));
    float2 b = ((const float2*)bias)[lane];
    ((float2*)(out + (size_t)wid * DD))[lane] = make_float2(ax * nr + b.x, ay * nr + b.y);
}

extern "C" void kernel_launch(void* const* d_in, const int* in_sizes, int n_in,
                              void* d_out, int out_size, void* d_ws, size_t ws_size,
                              hipStream_t stream) {
    const int* feat = (const int*)d_in[0];
    const int* src  = (const int*)d_in[1];
    const int* dst  = (const int*)d_in[2];
    const float* emb  = (const float*)d_in[3];
    const float* bias = (const float*)d_in[4];
    float* out = (float*)d_out;

    // Workspace layout (~20.5 MB; descending alignment)
    int* histD = (int*)d_ws;                          // NBUCK*NBLK
    int* histS = histD + NBUCK * NBLK;                // NBUCK*NBLK
    int* SD    = histS + NBUCK * NBLK;                // NBUCK (padded 800)
    int* SS    = SD + 800;
    int* baseD = SS + 800;
    int* baseS = baseD + 800;
    int* baseN = baseS + 800;                         // NN
    int* cntN  = baseN + NN;                          // NN
    unsigned int* sortedD = (unsigned int*)(cntN + NN);         // NE
    ushort2* h = (ushort2*)(sortedD + NE);            // NN*64 ushort2 (12.8 MB)
    unsigned short* srcfine = (unsigned short*)(h + (size_t)NN * 64); // NE ushort
    unsigned char* sortedS = (unsigned char*)(srcfine + NE);    // NE bytes

    hist_kernel<<<NBLK, 256, 0, stream>>>(src, dst, histD, histS);
    within_kernel<<<2 * NBUCK, NBLK, 0, stream>>>(histD, histS, SD, SS);
    scan_kernel<<<1, 1024, 0, stream>>>(SD, SS, baseD, baseS);
    scatter_kernel<<<NBLK, 256, 0, stream>>>(src, dst, histD, histS, baseD, baseS,
                                             sortedD, sortedS);
    finehb_kernel<<<2 * NBUCK, 256, 0, stream>>>(sortedD, sortedS, baseD, baseS, feat, emb,
                                                 baseN, cntN, srcfine, h);
    gatherA_kernel<<<(NN * 64 + 255) / 256, 256, 0, stream>>>(srcfine, baseN, cntN, h, bias, out);
}

// Round 10
// 83.246 us; speedup vs baseline: 1.6897x; 1.0386x over previous
//
#include <hip/hip_runtime.h>

#define NN 50000
#define NE 800000
#define DD 128
#define BSH 6
#define BSZ 64                                // nodes per bucket
#define NBUCK ((NN + BSZ - 1) / BSZ)          // 782
#define NBLK 256                              // edge-partition blocks
#define EPB ((NE + NBLK - 1) / NBLK)          // 3125

__device__ __forceinline__ unsigned short f2bf(float x) {
    unsigned u = __float_as_uint(x);
    unsigned r = u + 0x7FFF + ((u >> 16) & 1);   // round-to-nearest-even
    return (unsigned short)(r >> 16);
}
__device__ __forceinline__ float bf2f(unsigned short x) {
    return __uint_as_float((unsigned)x << 16);
}

// K1: per-block LDS histograms of dst>>6 and src>>6 (no global atomics)
__global__ void hist_kernel(const int* __restrict__ src, const int* __restrict__ dst,
                            int* __restrict__ histD, int* __restrict__ histS) {
    __shared__ int hD[NBUCK], hS[NBUCK];
    int t = threadIdx.x, blk = blockIdx.x;
    for (int b = t; b < NBUCK; b += 256) { hD[b] = 0; hS[b] = 0; }
    __syncthreads();
    int beg = blk * EPB, end = min(beg + EPB, NE);
    for (int i = beg + t; i < end; i += 256) {
        atomicAdd(&hD[dst[i] >> BSH], 1);
        atomicAdd(&hS[src[i] >> BSH], 1);
    }
    __syncthreads();
    for (int b = t; b < NBUCK; b += 256) {
        histD[b * NBLK + blk] = hD[b];
        histS[b * NBLK + blk] = hS[b];
    }
}

// K2: within-bin exclusive scan over the 256 block-entries (in place) + bin total.
__global__ void within_kernel(int* __restrict__ histD, int* __restrict__ histS,
                              int* __restrict__ SD, int* __restrict__ SS) {
    __shared__ int col[NBLK];
    int t = threadIdx.x, b = blockIdx.x;
    int* hist = (b < NBUCK) ? histD : histS;
    int* S = (b < NBUCK) ? SD : SS;
    int bin = (b < NBUCK) ? b : b - NBUCK;
    int v = hist[bin * NBLK + t];
    col[t] = v;
    __syncthreads();
    for (int off = 1; off < NBLK; off <<= 1) {
        int x = (t >= off) ? col[t - off] : 0;
        __syncthreads();
        col[t] += x;
        __syncthreads();
    }
    hist[bin * NBLK + t] = col[t] - v;          // exclusive within bin
    if (t == NBLK - 1) S[bin] = col[t];         // bin total
}

// K3: single block: exclusive scan of both bin-total arrays -> bucket bases.
__global__ void scan_kernel(const int* __restrict__ SD, const int* __restrict__ SS,
                            int* __restrict__ baseD, int* __restrict__ baseS) {
    __shared__ int s[1024];
    int t = threadIdx.x;
    for (int pass = 0; pass < 2; pass++) {
        const int* S = pass ? SS : SD;
        int* base = pass ? baseS : baseD;
        int v = (t < NBUCK) ? S[t] : 0;
        s[t] = v;
        __syncthreads();
        for (int off = 1; off < 1024; off <<= 1) {
            int x = (t >= off) ? s[t - off] : 0;
            __syncthreads();
            s[t] += x;
            __syncthreads();
        }
        if (t < NBUCK) base[t] = s[t] - v;
        __syncthreads();
    }
}

// K4: scatter edges into dst-buckets (packed src|lo<<16) and src_lo bytes into
// src-buckets; LDS cursors seeded with base[bin] + within-bin offset.
__global__ void scatter_kernel(const int* __restrict__ src, const int* __restrict__ dst,
                               const int* __restrict__ offsD, const int* __restrict__ offsS,
                               const int* __restrict__ baseD, const int* __restrict__ baseS,
                               unsigned int* __restrict__ sortedD,
                               unsigned char* __restrict__ sortedS) {
    __shared__ int curD[NBUCK], curS[NBUCK];
    int t = threadIdx.x, blk = blockIdx.x;
    for (int b = t; b < NBUCK; b += 256) {
        curD[b] = baseD[b] + offsD[b * NBLK + blk];
        curS[b] = baseS[b] + offsS[b * NBLK + blk];
    }
    __syncthreads();
    int beg = blk * EPB, end = min(beg + EPB, NE);
    for (int i = beg + t; i < end; i += 256) {
        int sv = src[i], dv = dst[i];
        int pD = atomicAdd(&curD[dv >> BSH], 1);
        sortedD[pD] = (unsigned)sv | ((unsigned)(dv & (BSZ - 1)) << 16);
        int pS = atomicAdd(&curS[sv >> BSH], 1);
        sortedS[pS] = (unsigned char)(sv & (BSZ - 1));
    }
}

// K5 fused: blocks [0,NBUCK) = finesort of dst-bucket; [NBUCK,2*NBUCK) = hbuild of
// src-bucket (half-wave float4 emb reads, ushort4 h writes).
__global__ void finehb_kernel(const unsigned int* __restrict__ sortedD,
                              const unsigned char* __restrict__ sortedS,
                              const int* __restrict__ baseD, const int* __restrict__ baseS,
                              const int* __restrict__ feat, const float* __restrict__ emb,
                              int* __restrict__ baseN, int* __restrict__ cntN,
                              unsigned short* __restrict__ srcfine,
                              ushort4* __restrict__ h4) {
    __shared__ int lh[BSZ], lcur[BSZ];
    int t = threadIdx.x;
    if (blockIdx.x < NBUCK) {
        int bin = blockIdx.x;
        int beg = baseD[bin];
        int end = (bin == NBUCK - 1) ? NE : baseD[bin + 1];
        if (t < BSZ) lh[t] = 0;
        __syncthreads();
        for (int i = beg + t; i < end; i += 256) atomicAdd(&lh[sortedD[i] >> 16], 1);
        __syncthreads();
        if (t < BSZ) {                     // wave 0: shfl exclusive scan of 64
            int v = lh[t];
            int x = v;
            for (int off = 1; off < 64; off <<= 1) {
                int y = __shfl_up(x, off);
                if (t >= off) x += y;
            }
            int excl = beg + x - v;
            lcur[t] = excl;
            int n = (bin << BSH) + t;
            if (n < NN) { baseN[n] = excl; cntN[n] = v; }
        }
        __syncthreads();
        for (int i = beg + t; i < end; i += 256) {
            unsigned e = sortedD[i];
            int pos = atomicAdd(&lcur[e >> 16], 1);
            srcfine[pos] = (unsigned short)(e & 0xFFFF);
        }
    } else {
        int bin = blockIdx.x - NBUCK;
        int beg = baseS[bin];
        int end = (bin == NBUCK - 1) ? NE : baseS[bin + 1];
        if (t < BSZ) lh[t] = 0;
        __syncthreads();
        for (int i = beg + t; i < end; i += 256) atomicAdd(&lh[sortedS[i]], 1);
        __syncthreads();
        int w = t >> 6, lane = t & 63;
        int half = lane >> 5, sl = lane & 31;
        for (int k = 0; k < 8; k++) {
            int lo = (w << 4) + (k << 1) + half;   // wave w owns 16 consecutive nodes
            int n = (bin << BSH) + lo;
            if (n < NN) {
                float nl = rsqrtf((float)max(lh[lo], 1));
                int f = feat[n];
                float4 v = ((const float4*)(emb + (size_t)f * DD))[sl];
                h4[(size_t)n * 32 + sl] =
                    make_ushort4(f2bf(v.x * nl), f2bf(v.y * nl), f2bf(v.z * nl), f2bf(v.w * nl));
            }
        }
    }
}

// K6: one wave per dst node, split into two half-waves. Each half-wave fetches a
// DIFFERENT edge's 256B h-row via ushort4 (8B x 32 lanes); 8 edges per iter with
// 4 independent loads/lane in flight. Cross-half shfl_xor reduce; float4 write.
__global__ void gatherA_kernel(const unsigned short* __restrict__ srcfine,
                               const int* __restrict__ baseN, const int* __restrict__ cntN,
                               const ushort4* __restrict__ h4, const float* __restrict__ bias,
                               float* __restrict__ out) {
    int wid = (blockIdx.x * blockDim.x + threadIdx.x) >> 6;
    int lane = threadIdx.x & 63;
    if (wid >= NN) return;
    int half = lane >> 5, sl = lane & 31;
    int cnt = cntN[wid];
    int beg = baseN[wid];
    float a0 = 0.f, a1 = 0.f, a2 = 0.f, a3 = 0.f;
    for (int b0 = 0; b0 < cnt; b0 += 64) {
        int m = min(cnt - b0, 64);
        int idx = (lane < m) ? (int)srcfine[beg + b0 + lane] : 0;
        int j = 0;
        for (; j + 7 < m; j += 8) {
            int s0 = __shfl(idx, j + half);
            int s1 = __shfl(idx, j + 2 + half);
            int s2 = __shfl(idx, j + 4 + half);
            int s3 = __shfl(idx, j + 6 + half);
            ushort4 v0 = h4[(size_t)s0 * 32 + sl];
            ushort4 v1 = h4[(size_t)s1 * 32 + sl];
            ushort4 v2 = h4[(size_t)s2 * 32 + sl];
            ushort4 v3 = h4[(size_t)s3 * 32 + sl];
            a0 += bf2f(v0.x) + bf2f(v1.x) + bf2f(v2.x) + bf2f(v3.x);
            a1 += bf2f(v0.y) + bf2f(v1.y) + bf2f(v2.y) + bf2f(v3.y);
            a2 += bf2f(v0.z) + bf2f(v1.z) + bf2f(v2.z) + bf2f(v3.z);
            a3 += bf2f(v0.w) + bf2f(v1.w) + bf2f(v2.w) + bf2f(v3.w);
        }
        for (; j + 1 < m; j += 2) {
            int s0 = __shfl(idx, j + half);
            ushort4 v0 = h4[(size_t)s0 * 32 + sl];
            a0 += bf2f(v0.x);
            a1 += bf2f(v0.y);
            a2 += bf2f(v0.z);
            a3 += bf2f(v0.w);
        }
        if (j < m) {                        // odd leftover: half 0 only
            int s0 = __shfl(idx, j);
            if (half == 0) {
                ushort4 v0 = h4[(size_t)s0 * 32 + sl];
                a0 += bf2f(v0.x);
                a1 += bf2f(v0.y);
                a2 += bf2f(v0.z);
                a3 += bf2f(v0.w);
            }
        }
    }
    a0 += __shfl_xor(a0, 32);
    a1 += __shfl_xor(a1, 32);
    a2 += __shfl_xor(a2, 32);
    a3 += __shfl_xor(a3, 32);
    if (half == 0) {
        float nr = rsqrtf((float)max(cnt, 1));
        float4 bi = ((const float4*)bias)[sl];
        ((float4*)(out + (size_t)wid * DD))[sl] =
            make_float4(a0 * nr + bi.x, a1 * nr + bi.y, a2 * nr + bi.z, a3 * nr + bi.w);
    }
}

extern "C" void kernel_launch(void* const* d_in, const int* in_sizes, int n_in,
                              void* d_out, int out_size, void* d_ws, size_t ws_size,
                              hipStream_t stream) {
    const int* feat = (const int*)d_in[0];
    const int* src  = (const int*)d_in[1];
    const int* dst  = (const int*)d_in[2];
    const float* emb  = (const float*)d_in[3];
    const float* bias = (const float*)d_in[4];
    float* out = (float*)d_out;

    // Workspace layout (~20.5 MB; descending alignment)
    int* histD = (int*)d_ws;                          // NBUCK*NBLK
    int* histS = histD + NBUCK * NBLK;                // NBUCK*NBLK
    int* SD    = histS + NBUCK * NBLK;                // NBUCK (padded 800)
    int* SS    = SD + 800;
    int* baseD = SS + 800;
    int* baseS = baseD + 800;
    int* baseN = baseS + 800;                         // NN
    int* cntN  = baseN + NN;                          // NN
    unsigned int* sortedD = (unsigned int*)(cntN + NN);         // NE
    ushort4* h4 = (ushort4*)(sortedD + NE);           // NN*32 ushort4 (12.8 MB)
    unsigned short* srcfine = (unsigned short*)(h4 + (size_t)NN * 32); // NE ushort
    unsigned char* sortedS = (unsigned char*)(srcfine + NE);    // NE bytes

    hist_kernel<<<NBLK, 256, 0, stream>>>(src, dst, histD, histS);
    within_kernel<<<2 * NBUCK, NBLK, 0, stream>>>(histD, histS, SD, SS);
    scan_kernel<<<1, 1024, 0, stream>>>(SD, SS, baseD, baseS);
    scatter_kernel<<<NBLK, 256, 0, stream>>>(src, dst, histD, histS, baseD, baseS,
                                             sortedD, sortedS);
    finehb_kernel<<<2 * NBUCK, 256, 0, stream>>>(sortedD, sortedS, baseD, baseS, feat, emb,
                                                 baseN, cntN, srcfine, h4);
    gatherA_kernel<<<(NN * 64 + 255) / 256, 256, 0, stream>>>(srcfine, baseN, cntN, h4, bias, out);
}